// Round 3
// baseline (35.720 us; speedup 1.0000x reference)
//
#include <hip/hip_runtime.h>

// Sigma = R * diag(exp(ls))^2 * R^T per gaussian.
// No-LDS variant: 4 gaussians/thread, all global accesses are contiguous
// per-thread float4 chunks (quat 64B, ls 48B, out 144B), no barriers.

constexpr int BLK = 256;

using f32x4 = __attribute__((ext_vector_type(4))) float;

__device__ __forceinline__ void covar_from(
    float w, float x, float y, float z,
    float e0, float e1, float e2, float* __restrict__ cv)
{
    float inv = rsqrtf(fmaf(w, w, fmaf(x, x, fmaf(y, y, z * z))));
    w *= inv; x *= inv; y *= inv; z *= inv;

    float s0 = __expf(e0), s1 = __expf(e1), s2 = __expf(e2);

    float r00 = 1.0f - 2.0f * (y * y + z * z);
    float r01 = 2.0f * (x * y - w * z);
    float r02 = 2.0f * (x * z + w * y);
    float r10 = 2.0f * (x * y + w * z);
    float r11 = 1.0f - 2.0f * (x * x + z * z);
    float r12 = 2.0f * (y * z - w * x);
    float r20 = 2.0f * (x * z - w * y);
    float r21 = 2.0f * (y * z + w * x);
    float r22 = 1.0f - 2.0f * (x * x + y * y);

    float m00 = r00 * s0, m01 = r01 * s1, m02 = r02 * s2;
    float m10 = r10 * s0, m11 = r11 * s1, m12 = r12 * s2;
    float m20 = r20 * s0, m21 = r21 * s1, m22 = r22 * s2;

    cv[0] = fmaf(m00, m00, fmaf(m01, m01, m02 * m02)); // c00
    cv[1] = fmaf(m00, m10, fmaf(m01, m11, m02 * m12)); // c01
    cv[2] = fmaf(m00, m20, fmaf(m01, m21, m02 * m22)); // c02
    cv[3] = fmaf(m10, m10, fmaf(m11, m11, m12 * m12)); // c11
    cv[4] = fmaf(m10, m20, fmaf(m11, m21, m12 * m22)); // c12
    cv[5] = fmaf(m20, m20, fmaf(m21, m21, m22 * m22)); // c22
}

__global__ __launch_bounds__(BLK) void gauss_covar_kernel(
    const f32x4* __restrict__ quats,   // [N] (w,x,y,z)
    const f32x4* __restrict__ ls4,     // log_scales viewed as float4
    f32x4*       __restrict__ out4,    // out viewed as float4
    int n4)                            // N/4 thread-work items
{
    const int t = blockIdx.x * BLK + threadIdx.x;
    if (t >= n4) return;

    // ---- loads: 4 quats (64B) + 12 log_scales (48B), contiguous per thread
    const f32x4* qp = quats + t * 4;
    f32x4 q0 = qp[0], q1 = qp[1], q2 = qp[2], q3 = qp[3];

    const f32x4* lp = ls4 + t * 3;
    f32x4 l0 = lp[0], l1 = lp[1], l2 = lp[2];

    float cv[4][6];
    covar_from(q0.x, q0.y, q0.z, q0.w, l0.x, l0.y, l0.z, cv[0]);
    covar_from(q1.x, q1.y, q1.z, q1.w, l0.w, l1.x, l1.y, cv[1]);
    covar_from(q2.x, q2.y, q2.z, q2.w, l1.z, l1.w, l2.x, cv[2]);
    covar_from(q3.x, q3.y, q3.z, q3.w, l2.y, l2.z, l2.w, cv[3]);

    // ---- stores: 36 floats = 9 float4, contiguous 144B per thread
    // per-gaussian row-major 3x3: c00 c01 c02 c01 c11 c12 c02 c12 c22
    f32x4* op = out4 + t * 9;
    f32x4 v;
    v = (f32x4){cv[0][0], cv[0][1], cv[0][2], cv[0][1]}; op[0] = v;
    v = (f32x4){cv[0][3], cv[0][4], cv[0][2], cv[0][4]}; op[1] = v;
    v = (f32x4){cv[0][5], cv[1][0], cv[1][1], cv[1][2]}; op[2] = v;
    v = (f32x4){cv[1][1], cv[1][3], cv[1][4], cv[1][2]}; op[3] = v;
    v = (f32x4){cv[1][4], cv[1][5], cv[2][0], cv[2][1]}; op[4] = v;
    v = (f32x4){cv[2][2], cv[2][1], cv[2][3], cv[2][4]}; op[5] = v;
    v = (f32x4){cv[2][2], cv[2][4], cv[2][5], cv[3][0]}; op[6] = v;
    v = (f32x4){cv[3][1], cv[3][2], cv[3][1], cv[3][3]}; op[7] = v;
    v = (f32x4){cv[3][4], cv[3][2], cv[3][4], cv[3][5]}; op[8] = v;
}

extern "C" void kernel_launch(void* const* d_in, const int* in_sizes, int n_in,
                              void* d_out, int out_size, void* d_ws, size_t ws_size,
                              hipStream_t stream) {
    const f32x4* quats = (const f32x4*)d_in[0];
    const f32x4* ls4   = (const f32x4*)d_in[1];
    f32x4*       out4  = (f32x4*)d_out;

    const int n  = in_sizes[0] / 4;          // N
    const int n4 = (n + 3) / 4;              // work items (N=2M -> exact)
    const int nblocks = (n4 + BLK - 1) / BLK;
    gauss_covar_kernel<<<nblocks, BLK, 0, stream>>>(quats, ls4, out4, n4);
}

// Round 4
// 24.866 us; speedup vs baseline: 1.4365x; 1.4365x over previous
//
#include <hip/hip_runtime.h>

// Sigma = R * diag(exp(ls))^2 * R^T per gaussian.
// Round-1 LDS-staged structure + persistent grid-stride blocks.
// All global accesses coalesced float4; plain cached (working set ~128 MB
// fits the 256 MB Infinity Cache across graph replays -> no nontemporal).

constexpr int BLK = 256;

using f32x4 = __attribute__((ext_vector_type(4))) float;

__global__ __launch_bounds__(BLK) void gauss_covar_kernel(
    const f32x4* __restrict__ quats,   // [N] (w,x,y,z)
    const f32x4* __restrict__ ls4,     // log_scales as float4 (N*3/4)
    f32x4*       __restrict__ out4,    // out as float4 (N*9/4)
    int ntiles, int n, int n_ls4, int n_out4)
{
    __shared__ float s_scale[BLK * 3];   // 3 KB
    __shared__ float s_out[BLK * 9];     // 9 KB

    const int tid = threadIdx.x;

    for (int tile = blockIdx.x; tile < ntiles; tile += gridDim.x) {
        // ---- cooperative float4 load of this tile's 768 log_scale floats
        if (tid < 192) {
            const int idx4 = tile * 192 + tid;
            if (idx4 < n_ls4) ((f32x4*)s_scale)[tid] = ls4[idx4];
        }
        __syncthreads();   // also orders prev tile's s_out reads before rewrite

        const int i = tile * BLK + tid;
        if (i < n) {
            f32x4 q = quats[i];            // coalesced 16B/lane
            float w = q.x, x = q.y, y = q.z, z = q.w;
            float inv = rsqrtf(fmaf(w, w, fmaf(x, x, fmaf(y, y, z * z))));
            w *= inv; x *= inv; y *= inv; z *= inv;

            // stride-3 LDS read: gcd(3,32)=1 -> conflict-free
            float s0 = __expf(s_scale[tid * 3 + 0]);
            float s1 = __expf(s_scale[tid * 3 + 1]);
            float s2 = __expf(s_scale[tid * 3 + 2]);

            float r00 = 1.0f - 2.0f * (y * y + z * z);
            float r01 = 2.0f * (x * y - w * z);
            float r02 = 2.0f * (x * z + w * y);
            float r10 = 2.0f * (x * y + w * z);
            float r11 = 1.0f - 2.0f * (x * x + z * z);
            float r12 = 2.0f * (y * z - w * x);
            float r20 = 2.0f * (x * z - w * y);
            float r21 = 2.0f * (y * z + w * x);
            float r22 = 1.0f - 2.0f * (x * x + y * y);

            float m00 = r00 * s0, m01 = r01 * s1, m02 = r02 * s2;
            float m10 = r10 * s0, m11 = r11 * s1, m12 = r12 * s2;
            float m20 = r20 * s0, m21 = r21 * s1, m22 = r22 * s2;

            float c00 = fmaf(m00, m00, fmaf(m01, m01, m02 * m02));
            float c01 = fmaf(m00, m10, fmaf(m01, m11, m02 * m12));
            float c02 = fmaf(m00, m20, fmaf(m01, m21, m02 * m22));
            float c11 = fmaf(m10, m10, fmaf(m11, m11, m12 * m12));
            float c12 = fmaf(m10, m20, fmaf(m11, m21, m12 * m22));
            float c22 = fmaf(m20, m20, fmaf(m21, m21, m22 * m22));

            // stride-9 LDS write: gcd(9,32)=1 -> conflict-free
            float* o = &s_out[tid * 9];
            o[0] = c00; o[1] = c01; o[2] = c02;
            o[3] = c01; o[4] = c11; o[5] = c12;
            o[6] = c02; o[7] = c12; o[8] = c22;
        }
        __syncthreads();

        // ---- cooperative float4 store of the tile's 2304 output floats
        const int obase4 = tile * 576;
#pragma unroll
        for (int r = 0; r < 3; ++r) {
            const int t = r * BLK + tid;       // need t < 576
            if (t < 576) {
                const int idx4 = obase4 + t;
                if (idx4 < n_out4) out4[idx4] = ((const f32x4*)s_out)[t];
            }
        }
    }
}

extern "C" void kernel_launch(void* const* d_in, const int* in_sizes, int n_in,
                              void* d_out, int out_size, void* d_ws, size_t ws_size,
                              hipStream_t stream) {
    const f32x4* quats = (const f32x4*)d_in[0];
    const f32x4* ls4   = (const f32x4*)d_in[1];
    f32x4*       out4  = (f32x4*)d_out;

    const int n      = in_sizes[0] / 4;            // N
    const int n_ls4  = in_sizes[1] / 4;            // N*3/4
    const int n_out4 = out_size / 4;               // N*9/4
    const int ntiles = (n + BLK - 1) / BLK;
    const int nblocks = (ntiles < 2048) ? ntiles : 2048;   // 8 blocks/CU
    gauss_covar_kernel<<<nblocks, BLK, 0, stream>>>(
        quats, ls4, out4, ntiles, n, n_ls4, n_out4);
}

// Round 5
// 24.459 us; speedup vs baseline: 1.4604x; 1.0166x over previous
//
#include <hip/hip_runtime.h>

// Sigma = R * diag(exp(ls))^2 * R^T per gaussian.
// 2 gaussians/thread MLP variant: doubles in-flight loads per thread while
// keeping every global access wave-coalesced float4. LDS staging for the
// stride-3 input and stride-9 output.

constexpr int BLK = 256;
constexpr int GPT = 2;                    // gaussians per thread
constexpr int TILE = BLK * GPT;           // 512 gaussians per block

using f32x4 = __attribute__((ext_vector_type(4))) float;

__device__ __forceinline__ void covar_from(
    float w, float x, float y, float z,
    float e0, float e1, float e2, float* __restrict__ cv)
{
    float inv = rsqrtf(fmaf(w, w, fmaf(x, x, fmaf(y, y, z * z))));
    w *= inv; x *= inv; y *= inv; z *= inv;

    float s0 = __expf(e0), s1 = __expf(e1), s2 = __expf(e2);

    float r00 = 1.0f - 2.0f * (y * y + z * z);
    float r01 = 2.0f * (x * y - w * z);
    float r02 = 2.0f * (x * z + w * y);
    float r10 = 2.0f * (x * y + w * z);
    float r11 = 1.0f - 2.0f * (x * x + z * z);
    float r12 = 2.0f * (y * z - w * x);
    float r20 = 2.0f * (x * z - w * y);
    float r21 = 2.0f * (y * z + w * x);
    float r22 = 1.0f - 2.0f * (x * x + y * y);

    float m00 = r00 * s0, m01 = r01 * s1, m02 = r02 * s2;
    float m10 = r10 * s0, m11 = r11 * s1, m12 = r12 * s2;
    float m20 = r20 * s0, m21 = r21 * s1, m22 = r22 * s2;

    cv[0] = fmaf(m00, m00, fmaf(m01, m01, m02 * m02)); // c00
    cv[1] = fmaf(m00, m10, fmaf(m01, m11, m02 * m12)); // c01
    cv[2] = fmaf(m00, m20, fmaf(m01, m21, m02 * m22)); // c02
    cv[3] = fmaf(m10, m10, fmaf(m11, m11, m12 * m12)); // c11
    cv[4] = fmaf(m10, m20, fmaf(m11, m21, m12 * m22)); // c12
    cv[5] = fmaf(m20, m20, fmaf(m21, m21, m22 * m22)); // c22
}

__global__ __launch_bounds__(BLK) void gauss_covar_kernel(
    const f32x4* __restrict__ quats,   // [N] (w,x,y,z)
    const f32x4* __restrict__ ls4,     // log_scales as float4 (N*3/4)
    f32x4*       __restrict__ out4,    // out as float4 (N*9/4)
    int n, int n_ls4, int n_out4)
{
    __shared__ float s_scale[TILE * 3];   // 6 KB
    __shared__ float s_out[TILE * 9];     // 18 KB

    const int tid  = threadIdx.x;
    const int base = blockIdx.x * TILE;

    // ---- issue ALL this thread's global loads up front (max MLP) ----
    // ls: TILE*3/4 = 384 float4 per block
    const int lbase4 = blockIdx.x * (TILE * 3 / 4);
    f32x4 lv0, lv1;
    bool lp0 = false, lp1 = false;
    {
        int i0 = lbase4 + tid;
        if (i0 < n_ls4)        { lv0 = ls4[i0]; lp0 = true; }
        int i1 = lbase4 + BLK + tid;
        if (tid < (TILE*3/4 - BLK) && i1 < n_ls4) { lv1 = ls4[i1]; lp1 = true; }
    }
    const int i0 = base + tid;
    const int i1 = base + BLK + tid;
    f32x4 q0, q1;
    bool qp0 = i0 < n, qp1 = i1 < n;
    if (qp0) q0 = quats[i0];
    if (qp1) q1 = quats[i1];

    if (lp0) ((f32x4*)s_scale)[tid] = lv0;
    if (lp1) ((f32x4*)s_scale)[BLK + tid] = lv1;
    __syncthreads();

#pragma unroll
    for (int g = 0; g < GPT; ++g) {
        const bool ok = g ? qp1 : qp0;
        if (!ok) continue;
        const f32x4 q = g ? q1 : q0;
        const int lt = g * BLK + tid;          // gaussian index within tile
        float cv[6];
        covar_from(q.x, q.y, q.z, q.w,
                   s_scale[lt * 3 + 0], s_scale[lt * 3 + 1], s_scale[lt * 3 + 2],
                   cv);
        float* o = &s_out[lt * 9];
        o[0] = cv[0]; o[1] = cv[1]; o[2] = cv[2];
        o[3] = cv[1]; o[4] = cv[3]; o[5] = cv[4];
        o[6] = cv[2]; o[7] = cv[4]; o[8] = cv[5];
    }
    __syncthreads();

    // ---- cooperative float4 store: TILE*9/4 = 1152 float4 per block ----
    const int obase4 = blockIdx.x * (TILE * 9 / 4);
#pragma unroll
    for (int r = 0; r < (TILE * 9 / 4 + BLK - 1) / BLK; ++r) {   // 5 rounds
        const int t = r * BLK + tid;
        if (t < TILE * 9 / 4) {
            const int idx4 = obase4 + t;
            if (idx4 < n_out4) out4[idx4] = ((const f32x4*)s_out)[t];
        }
    }
}

extern "C" void kernel_launch(void* const* d_in, const int* in_sizes, int n_in,
                              void* d_out, int out_size, void* d_ws, size_t ws_size,
                              hipStream_t stream) {
    const f32x4* quats = (const f32x4*)d_in[0];
    const f32x4* ls4   = (const f32x4*)d_in[1];
    f32x4*       out4  = (f32x4*)d_out;

    const int n      = in_sizes[0] / 4;            // N
    const int n_ls4  = in_sizes[1] / 4;            // N*3/4
    const int n_out4 = out_size / 4;               // N*9/4
    const int nblocks = (n + TILE - 1) / TILE;
    gauss_covar_kernel<<<nblocks, BLK, 0, stream>>>(quats, ls4, out4, n, n_ls4, n_out4);
}